// Round 10
// baseline (477.499 us; speedup 1.0000x reference)
//
#include <hip/hip_runtime.h>

#define N 8192
#define F 128
#define NEWF 64
#define ALPHA 0.2f
#define JSPLIT 4
#define JW (N / JSPLIT)      // 2048 j per block
#define RB 64                // rows per block (4 waves x 16)
#define PIECE 64             // j's per stage step (2 chunks of K=32)
#define NP (JW / PIECE)      // 32 pieces

typedef float f32x4 __attribute__((ext_vector_type(4)));
typedef short short8 __attribute__((ext_vector_type(8)));

typedef const __attribute__((address_space(1))) unsigned* gp_t;
typedef __attribute__((address_space(3))) unsigned* lp_t;
static __device__ __forceinline__ void gload_lds16(const void* g, void* l) {
    __builtin_amdgcn_global_load_lds((gp_t)g, (lp_t)l, 16, 0, 0);
}

// ---------------------------------------------------------------------------
// Kernel 1: h = X @ W (f32), s = h @ a_self, n = h @ a_neigh
// ---------------------------------------------------------------------------
__global__ void k_hsn(const float* __restrict__ X, const float* __restrict__ W,
                      const float* __restrict__ a_self, const float* __restrict__ a_neigh,
                      float* __restrict__ h, float* __restrict__ s, float* __restrict__ n) {
    int row = blockIdx.x * 4 + (threadIdx.x >> 6);
    int l = threadIdx.x & 63;
    const float* xr = X + (size_t)row * F;
    float acc = 0.0f;
#pragma unroll 8
    for (int f = 0; f < F; ++f) acc += xr[f] * W[f * NEWF + l];
    h[(size_t)row * NEWF + l] = acc;
    float ts = acc * a_self[l];
    float tn = acc * a_neigh[l];
#pragma unroll
    for (int off = 32; off; off >>= 1) {
        ts += __shfl_xor(ts, off);
        tn += __shfl_xor(tn, off);
    }
    if (l == 0) { s[row] = ts; n[row] = tn; }
}

// ---------------------------------------------------------------------------
// Kernel 2: transpose h, split into bf16 hi/lo planes hT[c][j]
// ---------------------------------------------------------------------------
__global__ void k_tr(const float* __restrict__ h, unsigned short* __restrict__ hThi,
                     unsigned short* __restrict__ hTlo) {
    __shared__ float tile[64][65];
    const int t = threadIdx.x;
    const int j0 = blockIdx.x * 64;
    {
        const int jr = t >> 2, cs = (t & 3) * 16;
        const float4* src = (const float4*)(h + (size_t)(j0 + jr) * NEWF + cs);
#pragma unroll
        for (int q = 0; q < 4; ++q) {
            float4 v = src[q];
            tile[jr][cs + q * 4 + 0] = v.x; tile[jr][cs + q * 4 + 1] = v.y;
            tile[jr][cs + q * 4 + 2] = v.z; tile[jr][cs + q * 4 + 3] = v.w;
        }
    }
    __syncthreads();
    {
        const int c = t >> 2, js = (t & 3) * 16;
        short8 hi0 = {}, hi1 = {}, lo0 = {}, lo1 = {};
#pragma unroll
        for (int k = 0; k < 16; ++k) {
            float v = tile[js + k][c];
            unsigned xb = __float_as_uint(v);
            short hb = (short)(xb >> 16);
            float lof = v - __uint_as_float(xb & 0xffff0000u);
            short lb = (short)(__float_as_uint(lof) >> 16);
            if (k < 8) { hi0[k] = hb; lo0[k] = lb; }
            else       { hi1[k - 8] = hb; lo1[k - 8] = lb; }
        }
        size_t off = (size_t)c * N + j0 + js;
        *(short8*)(hThi + off)     = hi0;
        *(short8*)(hThi + off + 8) = hi1;
        *(short8*)(hTlo + off)     = lo0;
        *(short8*)(hTlo + off + 8) = lo1;
    }
}

// ---------------------------------------------------------------------------
// Kernel 3: nmax = max_j n[j]
// ---------------------------------------------------------------------------
__global__ void k_nmax(const float* __restrict__ n, float* __restrict__ nmax) {
    __shared__ float red[1024];
    int t = threadIdx.x;
    float4 v0 = ((const float4*)n)[t];
    float4 v1 = ((const float4*)n)[t + 1024];
    float m = fmaxf(fmaxf(fmaxf(v0.x, v0.y), fmaxf(v0.z, v0.w)),
                    fmaxf(fmaxf(v1.x, v1.y), fmaxf(v1.z, v1.w)));
    red[t] = m;
    __syncthreads();
    for (int off = 512; off; off >>= 1) {
        if (t < off) red[t] = fmaxf(red[t], red[t + off]);
        __syncthreads();
    }
    if (t == 0) nmax[0] = red[0];
}

// ---------------------------------------------------------------------------
// Kernel 4: DIAGNOSTIC double-pass variant of r9's kernel.
//   The whole piece-pipeline runs TWICE, accumulating into the same
//   acc/zacc (numerator and denominator double -> identical output ratio).
//   Purpose: dur ~2x (>160us) so k_main finally surfaces in rocprof top-5
//   with full counters (VALUBusy / MfmaUtil / FETCH / conflicts / VGPR).
//   Structure is byte-identical to r9 otherwise (counted-vmcnt ring).
// ---------------------------------------------------------------------------
__global__ void __launch_bounds__(256, 2) k_main(
        const int* __restrict__ Araw, const float* __restrict__ s,
        const float* __restrict__ n, const float* __restrict__ nmaxp,
        const unsigned short* __restrict__ hThi, const unsigned short* __restrict__ hTlo,
        float* __restrict__ pacc, float* __restrict__ pz) {
    __shared__ __align__(16) char lds[73728];

    const int tid = threadIdx.x;
    const int w = tid >> 6, l = tid & 63;
    const int lr = l & 15, lg = l >> 4;

    const int rbk = blockIdx.x / JSPLIT;
    const int js  = blockIdx.x % JSPLIT;
    const int rblk = rbk * RB;
    const int r0 = rblk + w * 16;
    const int jb = js * JW;

    f32x4 acc0 = {0.f,0.f,0.f,0.f}, acc1 = {0.f,0.f,0.f,0.f};
    f32x4 acc2 = {0.f,0.f,0.f,0.f}, acc3 = {0.f,0.f,0.f,0.f};
    float zacc = 0.0f;

#define STAGE(piece, b)                                                        \
    {                                                                          \
        char* Ad = lds + (b) * 16384;                                          \
        char* Bd = lds + 32768 + (b) * 16384;                                  \
        const int jp = jb + (piece) * PIECE;                                   \
        _Pragma("unroll")                                                      \
        for (int q = 0; q < 4; ++q) {                                          \
            const int arw = q * 16 + (tid >> 4);                               \
            const int acol = ((tid & 15) * 16) ^ ((arw & 7) << 4);             \
            gload_lds16(Araw + (size_t)(rblk + arw) * N + jp + (acol >> 2),    \
                        Ad + q * 4096 + tid * 16);                             \
        }                                                                      \
        _Pragma("unroll")                                                      \
        for (int q = 0; q < 4; ++q) {                                          \
            const int brw = (q & 1) * 32 + (tid >> 3);                         \
            const int bcol = ((tid & 7) * 16) ^ ((brw & 7) << 4);              \
            const unsigned short* srcb =                                       \
                ((q >> 1) ? hTlo : hThi) + (size_t)brw * N + jp + (bcol >> 1); \
            gload_lds16(srcb, Bd + q * 4096 + tid * 16);                       \
        }                                                                      \
    }

#define CHUNK(p_, b_, ch_)                                                     \
    {                                                                          \
        const char* Ab = lds + (b_) * 16384;                                   \
        const char* Bb = lds + 32768 + (b_) * 16384;                           \
        const float* nsl = (const float*)(lds + 65536);                        \
        const int swz = (lr & 7) << 4;                                         \
        const int arow = w * 16 + lr;                                          \
        const int acol = (ch_) * 128 + lg * 32;                                \
        int4 av0 = *(const int4*)(Ab + arow * 256 + (acol ^ swz));             \
        int4 av1 = *(const int4*)(Ab + arow * 256 + ((acol + 16) ^ swz));      \
        const float* np0 = nsl + ((p_) * PIECE + (ch_) * 32 + lg * 8);         \
        float4 nv0 = *(const float4*)(np0);                                    \
        float4 nv1 = *(const float4*)(np0 + 4);                                \
        int   av[8] = {av0.x, av0.y, av0.z, av0.w, av1.x, av1.y, av1.z, av1.w};\
        float nf[8] = {nv0.x, nv0.y, nv0.z, nv0.w, nv1.x, nv1.y, nv1.z, nv1.w};\
        short8 ahi, alo;                                                       \
        _Pragma("unroll")                                                      \
        for (int j = 0; j < 8; ++j) {                                          \
            float t  = sval + nf[j];                                           \
            float lv = fmaxf(t, ALPHA * t);                                    \
            float ex = __expf(lv - Mv);                                        \
            ex = (av[j] != 0) ? ex : 0.0f;                                     \
            zacc += ex;                                                        \
            unsigned xb = __float_as_uint(ex);                                 \
            ahi[j] = (short)(xb >> 16);                                        \
            float lof = ex - __uint_as_float(xb & 0xffff0000u);                \
            alo[j] = (short)(__float_as_uint(lof) >> 16);                      \
        }                                                                      \
        const int bcol = ((ch_) * 64 + lg * 16) ^ swz;                         \
        short8 B0h = *(const short8*)(Bb + (lr +  0) * 128 + bcol);            \
        short8 B1h = *(const short8*)(Bb + (lr + 16) * 128 + bcol);            \
        short8 B2h = *(const short8*)(Bb + (lr + 32) * 128 + bcol);            \
        short8 B3h = *(const short8*)(Bb + (lr + 48) * 128 + bcol);            \
        short8 B0l = *(const short8*)(Bb + 8192 + (lr +  0) * 128 + bcol);     \
        short8 B1l = *(const short8*)(Bb + 8192 + (lr + 16) * 128 + bcol);     \
        short8 B2l = *(const short8*)(Bb + 8192 + (lr + 32) * 128 + bcol);     \
        short8 B3l = *(const short8*)(Bb + 8192 + (lr + 48) * 128 + bcol);     \
        acc0 = __builtin_amdgcn_mfma_f32_16x16x32_bf16(ahi, B0h, acc0, 0, 0, 0);\
        acc1 = __builtin_amdgcn_mfma_f32_16x16x32_bf16(ahi, B1h, acc1, 0, 0, 0);\
        acc2 = __builtin_amdgcn_mfma_f32_16x16x32_bf16(ahi, B2h, acc2, 0, 0, 0);\
        acc3 = __builtin_amdgcn_mfma_f32_16x16x32_bf16(ahi, B3h, acc3, 0, 0, 0);\
        acc0 = __builtin_amdgcn_mfma_f32_16x16x32_bf16(ahi, B0l, acc0, 0, 0, 0);\
        acc1 = __builtin_amdgcn_mfma_f32_16x16x32_bf16(ahi, B1l, acc1, 0, 0, 0);\
        acc2 = __builtin_amdgcn_mfma_f32_16x16x32_bf16(ahi, B2l, acc2, 0, 0, 0);\
        acc3 = __builtin_amdgcn_mfma_f32_16x16x32_bf16(ahi, B3l, acc3, 0, 0, 0);\
        acc0 = __builtin_amdgcn_mfma_f32_16x16x32_bf16(alo, B0h, acc0, 0, 0, 0);\
        acc1 = __builtin_amdgcn_mfma_f32_16x16x32_bf16(alo, B1h, acc1, 0, 0, 0);\
        acc2 = __builtin_amdgcn_mfma_f32_16x16x32_bf16(alo, B2h, acc2, 0, 0, 0);\
        acc3 = __builtin_amdgcn_mfma_f32_16x16x32_bf16(alo, B3h, acc3, 0, 0, 0);\
    }

#define COMPUTE(p_, b_) { CHUNK(p_, b_, 0); CHUNK(p_, b_, 1); }

    // ---- n-slab staged once (lds+65536, 8 KB) ----
    gload_lds16(n + jb + tid * 4,        lds + 65536 + tid * 16);
    gload_lds16(n + jb + 1024 + tid * 4, lds + 65536 + 4096 + tid * 16);
    const float sval = s[r0 + lr];
    const float tM = sval + nmaxp[0];
    const float Mv = fmaxf(tM, ALPHA * tM);

    for (int rep = 0; rep < 2; ++rep) {
        // protect dbuf from previous rep's readers
        __builtin_amdgcn_s_barrier();
        __builtin_amdgcn_sched_barrier(0);

        STAGE(0, 0);
        STAGE(1, 1);
        asm volatile("s_waitcnt vmcnt(0)" ::: "memory");
        __builtin_amdgcn_sched_barrier(0);
        __builtin_amdgcn_s_barrier();
        __builtin_amdgcn_sched_barrier(0);

        COMPUTE(0, 0);
        __builtin_amdgcn_s_barrier();
        __builtin_amdgcn_sched_barrier(0);
        STAGE(2, 0);

        for (int p = 1; p < NP - 1; ++p) {
            asm volatile("s_waitcnt vmcnt(8)" ::: "memory");
            __builtin_amdgcn_sched_barrier(0);
            __builtin_amdgcn_s_barrier();
            __builtin_amdgcn_sched_barrier(0);
            COMPUTE(p, p & 1);
            __builtin_amdgcn_s_barrier();
            __builtin_amdgcn_sched_barrier(0);
            if (p < NP - 2) STAGE(p + 2, p & 1);
        }

        asm volatile("s_waitcnt vmcnt(0)" ::: "memory");
        __builtin_amdgcn_sched_barrier(0);
        __builtin_amdgcn_s_barrier();
        __builtin_amdgcn_sched_barrier(0);
        COMPUTE(NP - 1, (NP - 1) & 1);
    }

#undef COMPUTE
#undef CHUNK
#undef STAGE

    // ---- z reduce over the 4 k-groups of each row ----
    zacc += __shfl_xor(zacc, 16);
    zacc += __shfl_xor(zacc, 32);

    // ---- write partials (both doubled -> ratio unchanged) ----
    float* pa = pacc + ((size_t)js * N + r0) * NEWF;
#pragma unroll
    for (int r = 0; r < 4; ++r) {
        int row = lg * 4 + r;
        pa[(size_t)row * NEWF +  0 + lr] = acc0[r];
        pa[(size_t)row * NEWF + 16 + lr] = acc1[r];
        pa[(size_t)row * NEWF + 32 + lr] = acc2[r];
        pa[(size_t)row * NEWF + 48 + lr] = acc3[r];
    }
    if (l < 16) pz[(size_t)js * N + r0 + lr] = zacc;
}

// ---------------------------------------------------------------------------
// Kernel 5: finalize — sum partials, divide, relu
// ---------------------------------------------------------------------------
__global__ void k_fin(const float* __restrict__ pacc, const float* __restrict__ pz,
                      float* __restrict__ out) {
    int t = blockIdx.x * 256 + threadIdx.x;     // 0 .. N*NEWF-1
    int i = t >> 6, k = t & 63;
    float v = 0.0f, z = 0.0f;
#pragma unroll
    for (int psl = 0; psl < JSPLIT; ++psl) {
        v += pacc[((size_t)psl * N + i) * NEWF + k];
        z += pz[(size_t)psl * N + i];
    }
    out[t] = fmaxf(v / z, 0.0f);
}

// ---------------------------------------------------------------------------
extern "C" void kernel_launch(void* const* d_in, const int* in_sizes, int n_in,
                              void* d_out, int out_size, void* d_ws, size_t ws_size,
                              hipStream_t stream) {
    const float* X       = (const float*)d_in[0];
    const int*   A       = (const int*)d_in[1];
    const float* W       = (const float*)d_in[2];
    const float* a_self  = (const float*)d_in[3];
    const float* a_neigh = (const float*)d_in[4];
    float* out = (float*)d_out;

    float* wsf = (float*)d_ws;
    float* h    = wsf;                        // N*NEWF f32 (2MB)
    float* s    = h + (size_t)N * NEWF;       // N
    float* nv   = s + N;                      // N
    float* nmax = nv + N;                     // 4
    unsigned short* hThi = (unsigned short*)(nmax + 4);   // N*NEWF ushort (1MB)
    unsigned short* hTlo = hThi + (size_t)N * NEWF;       // N*NEWF ushort (1MB)
    float* pacc = (float*)(hTlo + (size_t)N * NEWF);      // JSPLIT*N*NEWF f32 (8MB)
    float* pz   = pacc + (size_t)JSPLIT * N * NEWF;       // JSPLIT*N f32 (128KB)

    k_hsn <<<N / 4,        256, 0, stream>>>(X, W, a_self, a_neigh, h, s, nv);
    k_tr  <<<N / 64,       256, 0, stream>>>(h, hThi, hTlo);
    k_nmax<<<1,           1024, 0, stream>>>(nv, nmax);
    k_main<<<(N / RB) * JSPLIT, 256, 0, stream>>>(A, s, nv, nmax, hThi, hTlo, pacc, pz);
    k_fin <<<(N * NEWF) / 256, 256, 0, stream>>>(pacc, pz, out);
}